// Round 1
// baseline (29.941 us; speedup 1.0000x reference)
//
#include <hip/hip_runtime.h>

#define HH 512
#define WW 512
#define NPLANES 48   // B*C = 16*3

__device__ __forceinline__ void sort2(float& a, float& b) {
    float t = fminf(a, b);
    b = fmaxf(a, b);
    a = t;
}

__device__ __forceinline__ float median9(float p0, float p1, float p2,
                                         float p3, float p4, float p5,
                                         float p6, float p7, float p8) {
    // Paeth's 19-exchange median-of-9 network
    sort2(p1, p2); sort2(p4, p5); sort2(p7, p8);
    sort2(p0, p1); sort2(p3, p4); sort2(p6, p7);
    sort2(p1, p2); sort2(p4, p5); sort2(p7, p8);
    sort2(p0, p3); sort2(p5, p8); sort2(p4, p7);
    sort2(p3, p6); sort2(p1, p4); sort2(p2, p5);
    sort2(p4, p7); sort2(p4, p2); sort2(p6, p4);
    sort2(p4, p2);
    return p4;
}

__global__ __launch_bounds__(256) void MF_10943576670363_kernel(
    const float* __restrict__ in, float* __restrict__ out) {
    int idx = blockIdx.x * 256 + threadIdx.x;
    int t = idx & 127;          // col group (W/4 = 128 per row)
    int r = (idx >> 7) & 511;   // row
    int p = idx >> 16;          // plane (B*C)

    const float* base = in + (size_t)p * (HH * WW);
    int c0 = t * 4;

    float4 ctr[3];
    float lft[3], rgt[3];
#pragma unroll
    for (int dy = 0; dy < 3; ++dy) {
        int rr = r + dy - 1;
        if (rr < 0 || rr >= HH) {
            ctr[dy] = make_float4(0.f, 0.f, 0.f, 0.f);
            lft[dy] = 0.f;
            rgt[dy] = 0.f;
        } else {
            const float* rowp = base + rr * WW + c0;
            ctr[dy] = *reinterpret_cast<const float4*>(rowp);
            lft[dy] = (c0 > 0) ? rowp[-1] : 0.f;
            rgt[dy] = (c0 + 4 < WW) ? rowp[4] : 0.f;
        }
    }

    float4 o;
    o.x = median9(lft[0],   ctr[0].x, ctr[0].y,
                  lft[1],   ctr[1].x, ctr[1].y,
                  lft[2],   ctr[2].x, ctr[2].y);
    o.y = median9(ctr[0].x, ctr[0].y, ctr[0].z,
                  ctr[1].x, ctr[1].y, ctr[1].z,
                  ctr[2].x, ctr[2].y, ctr[2].z);
    o.z = median9(ctr[0].y, ctr[0].z, ctr[0].w,
                  ctr[1].y, ctr[1].z, ctr[1].w,
                  ctr[2].y, ctr[2].z, ctr[2].w);
    o.w = median9(ctr[0].z, ctr[0].w, rgt[0],
                  ctr[1].z, ctr[1].w, rgt[1],
                  ctr[2].z, ctr[2].w, rgt[2]);

    float* op = out + (size_t)p * (HH * WW) + r * WW + c0;
    *reinterpret_cast<float4*>(op) = o;
}

extern "C" void kernel_launch(void* const* d_in, const int* in_sizes, int n_in,
                              void* d_out, int out_size, void* d_ws, size_t ws_size,
                              hipStream_t stream) {
    const float* image = (const float*)d_in[0];
    float* out = (float*)d_out;
    // total threads = NPLANES * HH * (WW/4) = 48*512*128 = 3,145,728
    int total = NPLANES * HH * (WW / 4);
    int blocks = total / 256;  // 12288
    MF_10943576670363_kernel<<<blocks, 256, 0, stream>>>(image, out);
}

// Round 3
// 26.567 us; speedup vs baseline: 1.1270x; 1.1270x over previous
//
#include <hip/hip_runtime.h>

#define HH 512
#define WW 512
#define NP 48    // B*C
#define TW 8     // tile width  (2 x 4-vec)
#define TR 8     // tile rows per thread

typedef float f32x4 __attribute__((ext_vector_type(4)));

__device__ __forceinline__ float min3f(float a, float b, float c) {
    return fminf(fminf(a, b), c);
}
__device__ __forceinline__ float max3f(float a, float b, float c) {
    return fmaxf(fmaxf(a, b), c);
}
__device__ __forceinline__ float med3f(float a, float b, float c) {
    // med3(a,b,c) = max(min(a,b), min(max(a,b), c))
    return fmaxf(fminf(fmaxf(a, b), c), fminf(a, b));
}

// Branch-free row load: clamp row index so the load is always in-bounds,
// then select 0 for out-of-range rows / columns via cndmask.
__device__ __forceinline__ void load_row(float dst[10], const float* __restrict__ base,
                                         int rr, int c0) {
    int rcl = min(max(rr, 0), HH - 1);
    const float* rp = base + rcl * WW + c0;
    f32x4 a = *reinterpret_cast<const f32x4*>(rp);
    f32x4 b = *reinterpret_cast<const f32x4*>(rp + 4);
    float lv = rp[(c0 > 0) ? -1 : 0];
    float rv = rp[(c0 + TW < WW) ? TW : TW - 1];
    bool v = (rr >= 0) && (rr < HH);
    dst[0] = (v && c0 > 0) ? lv : 0.f;
    dst[1] = v ? a.x : 0.f;
    dst[2] = v ? a.y : 0.f;
    dst[3] = v ? a.z : 0.f;
    dst[4] = v ? a.w : 0.f;
    dst[5] = v ? b.x : 0.f;
    dst[6] = v ? b.y : 0.f;
    dst[7] = v ? b.z : 0.f;
    dst[8] = v ? b.w : 0.f;
    dst[9] = (v && (c0 + TW < WW)) ? rv : 0.f;
}

__global__ __launch_bounds__(256) void MF_10943576670363_kernel(
    const float* __restrict__ in, float* __restrict__ out) {
    int idx = blockIdx.x * 256 + threadIdx.x;
    int tx = idx & 63;          // W/TW = 64 col tiles
    int ty = (idx >> 6) & 63;   // H/TR = 64 row strips
    int p  = idx >> 12;         // plane

    int c0 = tx * TW;
    int r0 = ty * TR;
    const float* base = in + (size_t)p * (HH * WW);
    float* obase = out + (size_t)p * (HH * WW);

    float buf0[10], buf1[10], buf2[10];
    load_row(buf0, base, r0 - 1, c0);
    load_row(buf1, base, r0,     c0);

#define STEP(A, B, C, i)                                                        \
    {                                                                           \
        load_row(C, base, r0 + (i) + 1, c0);                                    \
        float lo[10], mi[10], hi[10];                                           \
        _Pragma("unroll") for (int j = 0; j < 10; ++j) {                        \
            lo[j] = min3f(A[j], B[j], C[j]);                                    \
            mi[j] = med3f(A[j], B[j], C[j]);                                    \
            hi[j] = max3f(A[j], B[j], C[j]);                                    \
        }                                                                       \
        f32x4 o0, o1;                                                           \
        o0.x = med3f(max3f(lo[0], lo[1], lo[2]), med3f(mi[0], mi[1], mi[2]),    \
                     min3f(hi[0], hi[1], hi[2]));                               \
        o0.y = med3f(max3f(lo[1], lo[2], lo[3]), med3f(mi[1], mi[2], mi[3]),    \
                     min3f(hi[1], hi[2], hi[3]));                               \
        o0.z = med3f(max3f(lo[2], lo[3], lo[4]), med3f(mi[2], mi[3], mi[4]),    \
                     min3f(hi[2], hi[3], hi[4]));                               \
        o0.w = med3f(max3f(lo[3], lo[4], lo[5]), med3f(mi[3], mi[4], mi[5]),    \
                     min3f(hi[3], hi[4], hi[5]));                               \
        o1.x = med3f(max3f(lo[4], lo[5], lo[6]), med3f(mi[4], mi[5], mi[6]),    \
                     min3f(hi[4], hi[5], hi[6]));                               \
        o1.y = med3f(max3f(lo[5], lo[6], lo[7]), med3f(mi[5], mi[6], mi[7]),    \
                     min3f(hi[5], hi[6], hi[7]));                               \
        o1.z = med3f(max3f(lo[6], lo[7], lo[8]), med3f(mi[6], mi[7], mi[8]),    \
                     min3f(hi[6], hi[7], hi[8]));                               \
        o1.w = med3f(max3f(lo[7], lo[8], lo[9]), med3f(mi[7], mi[8], mi[9]),    \
                     min3f(hi[7], hi[8], hi[9]));                               \
        float* op = obase + (r0 + (i)) * WW + c0;                               \
        __builtin_nontemporal_store(o0, reinterpret_cast<f32x4*>(op));          \
        __builtin_nontemporal_store(o1, reinterpret_cast<f32x4*>(op + 4));      \
    }

    STEP(buf0, buf1, buf2, 0)
    STEP(buf1, buf2, buf0, 1)
    STEP(buf2, buf0, buf1, 2)
    STEP(buf0, buf1, buf2, 3)
    STEP(buf1, buf2, buf0, 4)
    STEP(buf2, buf0, buf1, 5)
    STEP(buf0, buf1, buf2, 6)
    STEP(buf1, buf2, buf0, 7)
#undef STEP
}

extern "C" void kernel_launch(void* const* d_in, const int* in_sizes, int n_in,
                              void* d_out, int out_size, void* d_ws, size_t ws_size,
                              hipStream_t stream) {
    const float* image = (const float*)d_in[0];
    float* out = (float*)d_out;
    // threads = NP * (HH/TR) * (WW/TW) = 48*64*64 = 196608 -> 768 blocks
    int total = NP * (HH / TR) * (WW / TW);
    int blocks = total / 256;
    MF_10943576670363_kernel<<<blocks, 256, 0, stream>>>(image, out);
}

// Round 4
// 25.901 us; speedup vs baseline: 1.1560x; 1.0257x over previous
//
#include <hip/hip_runtime.h>

#define HH 512
#define WW 512
#define NP 48    // B*C
#define TW 8     // tile width  (2 x 4-vec)
#define TR 4     // output rows per thread (loads TR+2 = 6 rows up-front)

typedef float f32x4 __attribute__((ext_vector_type(4)));

__device__ __forceinline__ float min3f(float a, float b, float c) {
    return fminf(fminf(a, b), c);
}
__device__ __forceinline__ float max3f(float a, float b, float c) {
    return fmaxf(fmaxf(a, b), c);
}
__device__ __forceinline__ float med3f(float a, float b, float c) {
    return __builtin_amdgcn_fmed3f(a, b, c);  // exact median for finite inputs
}

// Branch-free row load: clamp row index so the load is always in-bounds,
// then select 0 for out-of-range rows / columns via cndmask.
__device__ __forceinline__ void load_row(float dst[10], const float* __restrict__ base,
                                         int rr, int c0) {
    int rcl = min(max(rr, 0), HH - 1);
    const float* rp = base + rcl * WW + c0;
    f32x4 a = *reinterpret_cast<const f32x4*>(rp);
    f32x4 b = *reinterpret_cast<const f32x4*>(rp + 4);
    float lv = rp[(c0 > 0) ? -1 : 0];
    float rv = rp[(c0 + TW < WW) ? TW : TW - 1];
    bool v = (rr >= 0) && (rr < HH);
    dst[0] = (v && c0 > 0) ? lv : 0.f;
    dst[1] = v ? a.x : 0.f;
    dst[2] = v ? a.y : 0.f;
    dst[3] = v ? a.z : 0.f;
    dst[4] = v ? a.w : 0.f;
    dst[5] = v ? b.x : 0.f;
    dst[6] = v ? b.y : 0.f;
    dst[7] = v ? b.z : 0.f;
    dst[8] = v ? b.w : 0.f;
    dst[9] = (v && (c0 + TW < WW)) ? rv : 0.f;
}

__global__ __launch_bounds__(256) void MF_10943576670363_kernel(
    const float* __restrict__ in, float* __restrict__ out) {
    int idx = blockIdx.x * 256 + threadIdx.x;
    int tx = idx & 63;          // W/TW = 64 col tiles
    int ty = (idx >> 6) & 127;  // H/TR = 128 row strips
    int p  = idx >> 13;         // plane

    int c0 = tx * TW;
    int r0 = ty * TR;
    const float* base = in + (size_t)p * (HH * WW);
    float* obase = out + (size_t)p * (HH * WW);

    // Load ALL 6 input rows up-front: 24 independent load instructions,
    // one latency window instead of a serial load->compute chain.
    float rb[6][10];
#pragma unroll
    for (int k = 0; k < 6; ++k) load_row(rb[k], base, r0 + k - 1, c0);

#pragma unroll
    for (int i = 0; i < TR; ++i) {
        const float* A = rb[i];
        const float* B = rb[i + 1];
        const float* C = rb[i + 2];
        float lo[10], mi[10], hi[10];
#pragma unroll
        for (int j = 0; j < 10; ++j) {
            lo[j] = min3f(A[j], B[j], C[j]);
            mi[j] = med3f(A[j], B[j], C[j]);
            hi[j] = max3f(A[j], B[j], C[j]);
        }
        f32x4 o0, o1;
        o0.x = med3f(max3f(lo[0], lo[1], lo[2]), med3f(mi[0], mi[1], mi[2]),
                     min3f(hi[0], hi[1], hi[2]));
        o0.y = med3f(max3f(lo[1], lo[2], lo[3]), med3f(mi[1], mi[2], mi[3]),
                     min3f(hi[1], hi[2], hi[3]));
        o0.z = med3f(max3f(lo[2], lo[3], lo[4]), med3f(mi[2], mi[3], mi[4]),
                     min3f(hi[2], hi[3], hi[4]));
        o0.w = med3f(max3f(lo[3], lo[4], lo[5]), med3f(mi[3], mi[4], mi[5]),
                     min3f(hi[3], hi[4], hi[5]));
        o1.x = med3f(max3f(lo[4], lo[5], lo[6]), med3f(mi[4], mi[5], mi[6]),
                     min3f(hi[4], hi[5], hi[6]));
        o1.y = med3f(max3f(lo[5], lo[6], lo[7]), med3f(mi[5], mi[6], mi[7]),
                     min3f(hi[5], hi[6], hi[7]));
        o1.z = med3f(max3f(lo[6], lo[7], lo[8]), med3f(mi[6], mi[7], mi[8]),
                     min3f(hi[6], hi[7], hi[8]));
        o1.w = med3f(max3f(lo[7], lo[8], lo[9]), med3f(mi[7], mi[8], mi[9]),
                     min3f(hi[7], hi[8], hi[9]));
        float* op = obase + (r0 + i) * WW + c0;
        __builtin_nontemporal_store(o0, reinterpret_cast<f32x4*>(op));
        __builtin_nontemporal_store(o1, reinterpret_cast<f32x4*>(op + 4));
    }
}

extern "C" void kernel_launch(void* const* d_in, const int* in_sizes, int n_in,
                              void* d_out, int out_size, void* d_ws, size_t ws_size,
                              hipStream_t stream) {
    const float* image = (const float*)d_in[0];
    float* out = (float*)d_out;
    // threads = NP * (HH/TR) * (WW/TW) = 48*128*64 = 393216 -> 1536 blocks
    int total = NP * (HH / TR) * (WW / TW);
    int blocks = total / 256;
    MF_10943576670363_kernel<<<blocks, 256, 0, stream>>>(image, out);
}

// Round 5
// 23.232 us; speedup vs baseline: 1.2888x; 1.1149x over previous
//
#include <hip/hip_runtime.h>

#define HH 512
#define WW 512
#define NP 48    // B*C
#define TW 8     // tile width  (2 x 4-vec); 64 lanes span the full 512-px row
#define TR 4     // output rows per thread (loads TR+2 = 6 rows up-front)

typedef float f32x4 __attribute__((ext_vector_type(4)));

__device__ __forceinline__ float min3f(float a, float b, float c) {
    return fminf(fminf(a, b), c);
}
__device__ __forceinline__ float max3f(float a, float b, float c) {
    return fmaxf(fmaxf(a, b), c);
}
__device__ __forceinline__ float med3f(float a, float b, float c) {
    return __builtin_amdgcn_fmed3f(a, b, c);  // exact median for finite inputs
}

// Branch-free row load. Halo elements come from neighbor LANES via shuffle —
// no strided scalar loads. A wave's 64 lanes cover exactly one 512-wide row
// span (lane == tx), so lane i-1 holds column c0-1 and lane i+1 holds c0+TW.
__device__ __forceinline__ void load_row(float dst[10], const float* __restrict__ base,
                                         int rr, int c0, int lane) {
    int rcl = min(max(rr, 0), HH - 1);
    const float* rp = base + rcl * WW + c0;
    f32x4 a = *reinterpret_cast<const f32x4*>(rp);
    f32x4 b = *reinterpret_cast<const f32x4*>(rp + 4);
    bool v = (rr >= 0) && (rr < HH);
    dst[1] = v ? a.x : 0.f;
    dst[2] = v ? a.y : 0.f;
    dst[3] = v ? a.z : 0.f;
    dst[4] = v ? a.w : 0.f;
    dst[5] = v ? b.x : 0.f;
    dst[6] = v ? b.y : 0.f;
    dst[7] = v ? b.z : 0.f;
    dst[8] = v ? b.w : 0.f;
    float lv = __shfl_up(dst[8], 1, 64);
    float rv = __shfl_down(dst[1], 1, 64);
    dst[0] = (lane > 0) ? lv : 0.f;   // c0==0 at lane 0 -> zero pad
    dst[9] = (lane < 63) ? rv : 0.f;  // c0+TW==WW at lane 63 -> zero pad
}

__global__ __launch_bounds__(256) void MF_10943576670363_kernel(
    const float* __restrict__ in, float* __restrict__ out) {
    // XCD-chunked bijective swizzle: 1536 blocks, 8 XCDs, 192 blocks/XCD.
    // Consecutive ty strips (sharing halo rows) stay on one XCD's L2.
    int bid = blockIdx.x;
    int cpx = gridDim.x >> 3;
    int swz = (bid & 7) * cpx + (bid >> 3);

    int idx = swz * 256 + threadIdx.x;
    int tx = idx & 63;          // W/TW = 64 col tiles == lane id
    int ty = (idx >> 6) & 127;  // H/TR = 128 row strips
    int p  = idx >> 13;         // plane

    int c0 = tx * TW;
    int r0 = ty * TR;
    const float* base = in + (size_t)p * (HH * WW);
    float* obase = out + (size_t)p * (HH * WW);

    // Load ALL 6 input rows up-front: independent loads, one latency window.
    float rb[6][10];
#pragma unroll
    for (int k = 0; k < 6; ++k) load_row(rb[k], base, r0 + k - 1, c0, tx);

#pragma unroll
    for (int i = 0; i < TR; ++i) {
        const float* A = rb[i];
        const float* B = rb[i + 1];
        const float* C = rb[i + 2];
        float lo[10], mi[10], hi[10];
#pragma unroll
        for (int j = 0; j < 10; ++j) {
            lo[j] = min3f(A[j], B[j], C[j]);
            mi[j] = med3f(A[j], B[j], C[j]);
            hi[j] = max3f(A[j], B[j], C[j]);
        }
        f32x4 o0, o1;
        o0.x = med3f(max3f(lo[0], lo[1], lo[2]), med3f(mi[0], mi[1], mi[2]),
                     min3f(hi[0], hi[1], hi[2]));
        o0.y = med3f(max3f(lo[1], lo[2], lo[3]), med3f(mi[1], mi[2], mi[3]),
                     min3f(hi[1], hi[2], hi[3]));
        o0.z = med3f(max3f(lo[2], lo[3], lo[4]), med3f(mi[2], mi[3], mi[4]),
                     min3f(hi[2], hi[3], hi[4]));
        o0.w = med3f(max3f(lo[3], lo[4], lo[5]), med3f(mi[3], mi[4], mi[5]),
                     min3f(hi[3], hi[4], hi[5]));
        o1.x = med3f(max3f(lo[4], lo[5], lo[6]), med3f(mi[4], mi[5], mi[6]),
                     min3f(hi[4], hi[5], hi[6]));
        o1.y = med3f(max3f(lo[5], lo[6], lo[7]), med3f(mi[5], mi[6], mi[7]),
                     min3f(hi[5], hi[6], hi[7]));
        o1.z = med3f(max3f(lo[6], lo[7], lo[8]), med3f(mi[6], mi[7], mi[8]),
                     min3f(hi[6], hi[7], hi[8]));
        o1.w = med3f(max3f(lo[7], lo[8], lo[9]), med3f(mi[7], mi[8], mi[9]),
                     min3f(hi[7], hi[8], hi[9]));
        float* op = obase + (r0 + i) * WW + c0;
        *reinterpret_cast<f32x4*>(op) = o0;       // normal stores: L2/L3 absorb
        *reinterpret_cast<f32x4*>(op + 4) = o1;
    }
}

extern "C" void kernel_launch(void* const* d_in, const int* in_sizes, int n_in,
                              void* d_out, int out_size, void* d_ws, size_t ws_size,
                              hipStream_t stream) {
    const float* image = (const float*)d_in[0];
    float* out = (float*)d_out;
    // threads = NP * (HH/TR) * (WW/TW) = 48*128*64 = 393216 -> 1536 blocks
    int total = NP * (HH / TR) * (WW / TW);
    int blocks = total / 256;
    MF_10943576670363_kernel<<<blocks, 256, 0, stream>>>(image, out);
}